// Round 1
// baseline (1363.678 us; speedup 1.0000x reference)
//
#include <hip/hip_runtime.h>

#define BB 8
#define TT 1024
#define NN 64
#define HH 8
#define LL 2
#define KSS 3
#define DD1 64
#define EPSV 1e-6f

// ---------- swizzled 64x64 f32 LDS tiles ----------
// element (row, n) lives at word row*64 + ((n>>2 ^ ((row>>2)&15))<<2) + (n&3)

__device__ __forceinline__ void load_tile_swz(float* __restrict__ s,
                                              const float* __restrict__ g, int tid) {
#pragma unroll
  for (int i = 0; i < 4; ++i) {
    int idx = tid + i * 256;            // 0..1023 float4s
    int r = idx >> 4, c = idx & 15;
    float4 v = *(const float4*)(g + r * 64 + c * 4);
    int ch = c ^ ((r >> 2) & 15);
    *(float4*)(s + r * 64 + ch * 4) = v;
  }
}

// C[r][c] += sum_n A[4rg+r][n] * B[4cg+c][n]
__device__ __forceinline__ void gemm_nt(float (&acc)[4][4], const float* __restrict__ A,
                                        const float* __restrict__ Bm, int rg, int cg) {
#pragma unroll 4
  for (int n0 = 0; n0 < 64; n0 += 4) {
    int ck = n0 >> 2;
    float a[4][4], b[4][4];
#pragma unroll
    for (int r = 0; r < 4; ++r)
      *(float4*)a[r] = *(const float4*)(A + (4 * rg + r) * 64 + ((ck ^ rg) << 2));
#pragma unroll
    for (int c = 0; c < 4; ++c)
      *(float4*)b[c] = *(const float4*)(Bm + (4 * cg + c) * 64 + ((ck ^ cg) << 2));
#pragma unroll
    for (int r = 0; r < 4; ++r)
#pragma unroll
      for (int c = 0; c < 4; ++c)
#pragma unroll
        for (int j = 0; j < 4; ++j) acc[r][c] = fmaf(a[r][j], b[c][j], acc[r][c]);
  }
}

// C[r][c] += sum_u A[4rg+r][u] * B[u][4cg+c]
__device__ __forceinline__ void gemm_nn(float (&acc)[4][4], const float* __restrict__ A,
                                        const float* __restrict__ Bm, int rg, int cg) {
#pragma unroll 4
  for (int u0 = 0; u0 < 64; u0 += 4) {
    int ck = u0 >> 2;
    float a[4][4], b[4][4];
#pragma unroll
    for (int r = 0; r < 4; ++r)
      *(float4*)a[r] = *(const float4*)(A + (4 * rg + r) * 64 + ((ck ^ rg) << 2));
#pragma unroll
    for (int s = 0; s < 4; ++s)
      *(float4*)b[s] = *(const float4*)(Bm + (u0 + s) * 64 + ((cg ^ ck) << 2));
#pragma unroll
    for (int r = 0; r < 4; ++r)
#pragma unroll
      for (int c = 0; c < 4; ++c)
#pragma unroll
        for (int s = 0; s < 4; ++s) acc[r][c] = fmaf(a[r][s], b[s][c], acc[r][c]);
  }
}

// C[a][d] += sum_r A[r][4rg+a] * B[r][4cg+d]
__device__ __forceinline__ void gemm_tn(float (&acc)[4][4], const float* __restrict__ A,
                                        const float* __restrict__ Bm, int rg, int cg) {
#pragma unroll 4
  for (int r0 = 0; r0 < 64; r0 += 4) {
    int ck = r0 >> 2;
    float a[4][4], b[4][4];
#pragma unroll
    for (int s = 0; s < 4; ++s) {
      *(float4*)a[s] = *(const float4*)(A + (r0 + s) * 64 + ((rg ^ ck) << 2));
      *(float4*)b[s] = *(const float4*)(Bm + (r0 + s) * 64 + ((cg ^ ck) << 2));
    }
#pragma unroll
    for (int aa = 0; aa < 4; ++aa)
#pragma unroll
      for (int d = 0; d < 4; ++d)
#pragma unroll
        for (int s = 0; s < 4; ++s) acc[aa][d] = fmaf(a[s][aa], b[s][d], acc[aa][d]);
  }
}

__device__ __forceinline__ float red_max16(float v) {
#pragma unroll
  for (int m = 1; m < 16; m <<= 1) v = fmaxf(v, __shfl_xor(v, m, 64));
  return v;
}
__device__ __forceinline__ float red_sum16(float v) {
#pragma unroll
  for (int m = 1; m < 16; m <<= 1) v += __shfl_xor(v, m, 64);
  return v;
}

// ---------- kernels ----------

__global__ void k_addpos(const float* __restrict__ in, const float* __restrict__ pe,
                         float* __restrict__ x, int total) {
  int idx = blockIdx.x * 256 + threadIdx.x;
  if (idx < total) {
    int tn = idx & (TT * NN - 1);
    x[idx] = in[idx] + pe[tn];
  }
}

__global__ void k_k3s(const float* __restrict__ K3, const float* __restrict__ sclwl,
                      float* __restrict__ K3s) {
  int idx = blockIdx.x * 256 + threadIdx.x;  // < 4096
  int n = idx >> 6, m = idx & 63;
  K3s[idx] = K3[n * 192 + m] * sclwl[0] + K3[n * 192 + 64 + m] * sclwl[1] +
             K3[n * 192 + 128 + m] * sclwl[2];
}

__global__ __launch_bounds__(64) void k_gconv(
    const float* __restrict__ x, const float* __restrict__ K3,
    const float* __restrict__ qwl, const float* __restrict__ qbl,
    const float* __restrict__ kwl, const float* __restrict__ kbl,
    const float* __restrict__ vwl, const float* __restrict__ vbl,
    float* __restrict__ xq, float* __restrict__ xk, float* __restrict__ xv) {
  __shared__ float sx[64];
  int lane = threadIdx.x;
  size_t bt = blockIdx.x;
  size_t b = bt >> 10, t = bt & 1023;
  float xm = x[bt * 64 + lane];
  sx[lane] = xm;
  __syncthreads();
  float a0 = 0.f, a1 = 0.f, a2 = 0.f;
#pragma unroll 4
  for (int n = 0; n < 64; ++n) {
    float xn = sx[n];
    a0 = fmaf(xn, K3[n * 192 + lane], a0);
    a1 = fmaf(xn, K3[n * 192 + 64 + lane], a1);
    a2 = fmaf(xn, K3[n * 192 + 128 + lane], a2);
  }
#pragma unroll
  for (int hh = 0; hh < HH; ++hh) {
    size_t off = (((size_t)b * HH + hh) * TT + t) * 64 + lane;
    float q = fmaf(qwl[hh * 3 + 0], a0,
              fmaf(qwl[hh * 3 + 1], a1, fmaf(qwl[hh * 3 + 2], a2, qbl[hh] + xm)));
    xq[off] = fmaxf(q, 0.f);
    float k = fmaf(kwl[hh * 3 + 0], a0,
              fmaf(kwl[hh * 3 + 1], a1, fmaf(kwl[hh * 3 + 2], a2, kbl[hh] + xm)));
    xk[off] = fmaxf(k, 0.f);
    float v = fmaf(vwl[hh * 3 + 0], a0,
              fmaf(vwl[hh * 3 + 1], a1, fmaf(vwl[hh * 3 + 2], a2, vbl[hh] + xm)));
    xv[off] = fmaxf(v, 0.f);
  }
}

// pass A: flash attention rows (online softmax) + save m,l
__global__ __launch_bounds__(256) void k_attn(
    const float* __restrict__ xk, const float* __restrict__ xq, const float* __restrict__ xv,
    float* __restrict__ auv, float* __restrict__ mrow, float* __restrict__ lrow) {
  __shared__ float sk[4096], sq[4096], sv[4096], sp[4096];
  int tid = threadIdx.x;
  int blk = blockIdx.x;
  int bh = blk >> 4;
  int t0 = (blk & 15) << 6;
  load_tile_swz(sk, xk + ((size_t)bh * TT + t0) * NN, tid);
  int rg = tid >> 4, cg = tid & 15;
  float o[4][4] = {};
  float mr[4], lr[4];
#pragma unroll
  for (int r = 0; r < 4; ++r) { mr[r] = -3.0e38f; lr[r] = 0.f; }
  for (int ut = 0; ut < 16; ++ut) {
    __syncthreads();
    load_tile_swz(sq, xq + ((size_t)bh * TT + ut * 64) * NN, tid);
    load_tile_swz(sv, xv + ((size_t)bh * TT + ut * 64) * NN, tid);
    __syncthreads();
    float s[4][4] = {};
    gemm_nt(s, sk, sq, rg, cg);
    const float scale = 1.0f / 64.0f;
#pragma unroll
    for (int r = 0; r < 4; ++r) {
      float tm = -3.0e38f;
#pragma unroll
      for (int c = 0; c < 4; ++c) { s[r][c] *= scale; tm = fmaxf(tm, s[r][c]); }
      tm = red_max16(tm);
      float mnew = fmaxf(mr[r], tm);
      float f = __expf(mr[r] - mnew);
      float ps = 0.f;
#pragma unroll
      for (int c = 0; c < 4; ++c) { s[r][c] = __expf(s[r][c] - mnew); ps += s[r][c]; }
      ps = red_sum16(ps);
      lr[r] = lr[r] * f + ps;
      mr[r] = mnew;
#pragma unroll
      for (int c = 0; c < 4; ++c) o[r][c] *= f;
    }
#pragma unroll
    for (int r = 0; r < 4; ++r)
      *(float4*)(sp + (4 * rg + r) * 64 + ((cg ^ rg) << 2)) =
          make_float4(s[r][0], s[r][1], s[r][2], s[r][3]);
    __syncthreads();
    gemm_nn(o, sp, sv, rg, cg);
  }
#pragma unroll
  for (int r = 0; r < 4; ++r) {
    int t = t0 + 4 * rg + r;
    float il = 1.0f / lr[r];
    float4 vo = make_float4(o[r][0] * il, o[r][1] * il, o[r][2] * il, o[r][3] * il);
    *(float4*)(auv + ((size_t)bh * TT + t) * NN + 4 * cg) = vo;
    if (cg == 0) {
      mrow[(size_t)bh * TT + t] = mr[r];
      lrow[(size_t)bh * TT + t] = lr[r];
    }
  }
}

// pass B: h1[c,d] = relu( sum_r P[r,c] * W1[r,d] + b1[d] ), P from saved m,l
__global__ __launch_bounds__(256) void k_h1(
    const float* __restrict__ xk, const float* __restrict__ xq,
    const float* __restrict__ mrow, const float* __restrict__ lrow,
    const float* __restrict__ tqW1l, const float* __restrict__ tqb1l,
    float* __restrict__ h1) {
  __shared__ float sk[4096], sq[4096], sw[4096], sp[4096];
  int tid = threadIdx.x, blk = blockIdx.x;
  int bh = blk >> 4;
  int h = bh & (HH - 1);
  int c0 = (blk & 15) << 6;
  load_tile_swz(sq, xq + ((size_t)bh * TT + c0) * NN, tid);
  int rg = tid >> 4, cg = tid & 15;
  float acc[4][4] = {};
  for (int rt = 0; rt < 16; ++rt) {
    __syncthreads();
    int r0 = rt << 6;
    load_tile_swz(sk, xk + ((size_t)bh * TT + r0) * NN, tid);
    load_tile_swz(sw, tqW1l + ((size_t)h * TT + r0) * DD1, tid);
    __syncthreads();
    float s[4][4] = {};
    gemm_nt(s, sk, sq, rg, cg);
    const float scale = 1.0f / 64.0f;
#pragma unroll
    for (int r = 0; r < 4; ++r) {
      int rr = r0 + 4 * rg + r;
      float m = mrow[(size_t)bh * TT + rr];
      float il = 1.0f / lrow[(size_t)bh * TT + rr];
#pragma unroll
      for (int c = 0; c < 4; ++c) s[r][c] = __expf(s[r][c] * scale - m) * il;
      *(float4*)(sp + (4 * rg + r) * 64 + ((cg ^ rg) << 2)) =
          make_float4(s[r][0], s[r][1], s[r][2], s[r][3]);
    }
    __syncthreads();
    gemm_tn(acc, sp, sw, rg, cg);
  }
#pragma unroll
  for (int a = 0; a < 4; ++a) {
    int t = c0 + 4 * rg + a;
    float tmp[4];
#pragma unroll
    for (int d = 0; d < 4; ++d)
      tmp[d] = fmaxf(acc[a][d] + tqb1l[(size_t)h * DD1 + 4 * cg + d], 0.f);
    *(float4*)(h1 + ((size_t)bh * TT + t) * DD1 + 4 * cg) =
        make_float4(tmp[0], tmp[1], tmp[2], tmp[3]);
  }
}

// h2 = relu(h1@W2+b2); z = h2@W3+b3; g = softmax(z); ho = g0*auv + g1*xv (in-place auv)
__global__ __launch_bounds__(256) void k_gate(
    const float* __restrict__ h1, const float* __restrict__ xv,
    const float* __restrict__ W2l, const float* __restrict__ b2l,
    const float* __restrict__ W3l, const float* __restrict__ b3l,
    float* __restrict__ auv) {
  __shared__ float sh1[4][64];
  int tid = threadIdx.x;
  int w = tid >> 6;
  int d = tid & 63;
  size_t blk = blockIdx.x;
  size_t bh = blk >> 8;
  int t = (int)((blk & 255) << 2) + w;
  int h = (int)(bh & (HH - 1));
  size_t rowoff = (bh * TT + (size_t)t) * 64;
  sh1[w][d] = h1[rowoff + d];
  __syncthreads();
  float acc = b2l[h * 64 + d];
  const float* W2 = W2l + (size_t)h * 64 * 64;
#pragma unroll 8
  for (int e = 0; e < 64; ++e) acc = fmaf(sh1[w][e], W2[e * 64 + d], acc);
  acc = fmaxf(acc, 0.f);
  float z0 = acc * W3l[((size_t)h * 64 + d) * 2 + 0];
  float z1 = acc * W3l[((size_t)h * 64 + d) * 2 + 1];
#pragma unroll
  for (int m = 1; m < 64; m <<= 1) {
    z0 += __shfl_xor(z0, m, 64);
    z1 += __shfl_xor(z1, m, 64);
  }
  z0 += b3l[h * 2 + 0];
  z1 += b3l[h * 2 + 1];
  float g0 = 1.0f / (1.0f + __expf(z1 - z0));
  float g1 = 1.0f - g0;
  auv[rowoff + d] = g0 * auv[rowoff + d] + g1 * xv[rowoff + d];
}

__global__ __launch_bounds__(64) void k_merge(
    const float* __restrict__ x, const float* __restrict__ ho,
    const float* __restrict__ Wltl, const float* __restrict__ g1l,
    const float* __restrict__ b1l, float* __restrict__ out1) {
  __shared__ float sho[512];
  int lane = threadIdx.x;
  size_t bt = blockIdx.x;
  size_t b = bt >> 10, t = bt & 1023;
#pragma unroll
  for (int i = 0; i < 8; ++i) {
    int idx = lane + i * 64;
    int hh = idx >> 6, n = idx & 63;
    sho[idx] = ho[(((size_t)b * HH + hh) * TT + t) * 64 + n];
  }
  __syncthreads();
  float acc = x[bt * 64 + lane];
#pragma unroll 8
  for (int hn = 0; hn < 512; ++hn) acc = fmaf(sho[hn], Wltl[hn * 64 + lane], acc);
  float mu = acc;
#pragma unroll
  for (int m = 1; m < 64; m <<= 1) mu += __shfl_xor(mu, m, 64);
  mu *= (1.0f / 64.0f);
  float dd = acc - mu;
  float var = dd * dd;
#pragma unroll
  for (int m = 1; m < 64; m <<= 1) var += __shfl_xor(var, m, 64);
  var *= (1.0f / 64.0f);
  out1[bt * 64 + lane] = dd * rsqrtf(var + EPSV) * g1l[lane] + b1l[lane];
}

__global__ __launch_bounds__(64) void k_ffn(
    const float* __restrict__ out1, const float* __restrict__ K3sl,
    const float* __restrict__ sclb_l, const float* __restrict__ elWl,
    const float* __restrict__ elbl, const float* __restrict__ g2l,
    const float* __restrict__ b2l, float* __restrict__ xout) {
  __shared__ float so[64], sf[64];
  int lane = threadIdx.x;
  size_t bt = blockIdx.x;
  float o1 = out1[bt * 64 + lane];
  so[lane] = o1;
  __syncthreads();
  float gc = 0.f;
#pragma unroll 8
  for (int n = 0; n < 64; ++n) gc = fmaf(so[n], K3sl[n * 64 + lane], gc);
  float f1 = fmaxf(gc + sclb_l[0] + o1, 0.f);
  sf[lane] = f1;
  __syncthreads();
  float f2 = elbl[lane];
#pragma unroll 8
  for (int e = 0; e < 64; ++e) f2 = fmaf(sf[e], elWl[e * 64 + lane], f2);
  float v = o1 + f2;
  float mu = v;
#pragma unroll
  for (int m = 1; m < 64; m <<= 1) mu += __shfl_xor(mu, m, 64);
  mu *= (1.0f / 64.0f);
  float dd = v - mu;
  float var = dd * dd;
#pragma unroll
  for (int m = 1; m < 64; m <<= 1) var += __shfl_xor(var, m, 64);
  var *= (1.0f / 64.0f);
  xout[bt * 64 + lane] = dd * rsqrtf(var + EPSV) * g2l[lane] + b2l[lane];
}

__global__ __launch_bounds__(64) void k_final(
    const float* __restrict__ x, const float* __restrict__ fW1,
    const float* __restrict__ fb1, const float* __restrict__ fW2,
    const float* __restrict__ fb2, float* __restrict__ out) {
  __shared__ float pl[64];
  int lane = threadIdx.x;
  size_t b = blockIdx.x;
  float s = 0.f;
  for (int t = 0; t < TT; ++t) s += x[((size_t)b * TT + t) * 64 + lane];
  pl[lane] = s * (1.0f / TT);
  __syncthreads();
  float hv = 0.f;
  if (lane < 32) {
    hv = fb1[lane];
#pragma unroll 8
    for (int n = 0; n < 64; ++n) hv = fmaf(pl[n], fW1[n * 32 + lane], hv);
    hv = fmaxf(hv, 0.f) * fW2[lane];
  }
#pragma unroll
  for (int m = 1; m < 64; m <<= 1) hv += __shfl_xor(hv, m, 64);
  if (lane == 0) out[b] = hv + fb2[0];
}

extern "C" void kernel_launch(void* const* d_in, const int* in_sizes, int n_in,
                              void* d_out, int out_size, void* d_ws, size_t ws_size,
                              hipStream_t stream) {
  const float* inputs = (const float*)d_in[0];
  const float* pos_emb = (const float*)d_in[1];
  const float* K3 = (const float*)d_in[2];
  const float* qw = (const float*)d_in[3];
  const float* qb = (const float*)d_in[4];
  const float* kw = (const float*)d_in[5];
  const float* kb = (const float*)d_in[6];
  const float* vw = (const float*)d_in[7];
  const float* vb = (const float*)d_in[8];
  const float* tqW1 = (const float*)d_in[9];
  const float* tqb1 = (const float*)d_in[10];
  const float* tqW2 = (const float*)d_in[11];
  const float* tqb2 = (const float*)d_in[12];
  const float* tqW3 = (const float*)d_in[13];
  const float* tqb3 = (const float*)d_in[14];
  const float* Wlt = (const float*)d_in[15];
  const float* ln1g = (const float*)d_in[16];
  const float* ln1b = (const float*)d_in[17];
  const float* ln2g = (const float*)d_in[18];
  const float* ln2b = (const float*)d_in[19];
  const float* sclw = (const float*)d_in[20];
  const float* sclb = (const float*)d_in[21];
  const float* elW = (const float*)d_in[22];
  const float* elb = (const float*)d_in[23];
  const float* fW1 = (const float*)d_in[24];
  const float* fb1 = (const float*)d_in[25];
  const float* fW2 = (const float*)d_in[26];
  const float* fb2 = (const float*)d_in[27];
  float* out = (float*)d_out;
  float* ws = (float*)d_ws;

  // scaled Chebyshev kernels per layer
  for (int l = 0; l < LL; ++l)
    k_k3s<<<16, 256, 0, stream>>>(K3, sclw + l * KSS, ws + (size_t)l * 4096);

  const size_t base = 2 * 4096;
  const size_t TN = (size_t)TT * NN;
  const size_t HTN = (size_t)HH * TT * NN;
  const size_t per_b = 2 * TN + 5 * HTN + 2 * (size_t)HH * TT;
  size_t avail = ws_size / sizeof(float);
  avail = (avail > base) ? avail - base : 0;
  int Bc = (int)(avail / per_b);
  if (Bc > BB) Bc = BB;
  if (Bc < 1) Bc = 1;

  for (int b0 = 0; b0 < BB; b0 += Bc) {
    int bc = (BB - b0 < Bc) ? (BB - b0) : Bc;
    float* x = ws + base;
    float* out1 = x + (size_t)bc * TN;
    float* xq = out1 + (size_t)bc * TN;
    float* xk = xq + (size_t)bc * HTN;
    float* xv = xk + (size_t)bc * HTN;
    float* auv = xv + (size_t)bc * HTN;
    float* h1 = auv + (size_t)bc * HTN;
    float* mrow = h1 + (size_t)bc * HTN;
    float* lrow = mrow + (size_t)bc * HH * TT;

    int total = bc * (int)TN;
    k_addpos<<<(total + 255) / 256, 256, 0, stream>>>(inputs + (size_t)b0 * TN, pos_emb, x,
                                                      total);
    for (int l = 0; l < LL; ++l) {
      k_gconv<<<bc * TT, 64, 0, stream>>>(x, K3, qw + l * HH * KSS, qb + l * HH,
                                          kw + l * HH * KSS, kb + l * HH,
                                          vw + l * HH * KSS, vb + l * HH, xq, xk, xv);
      k_attn<<<bc * HH * (TT / 64), 256, 0, stream>>>(xk, xq, xv, auv, mrow, lrow);
      k_h1<<<bc * HH * (TT / 64), 256, 0, stream>>>(
          xk, xq, mrow, lrow, tqW1 + (size_t)l * HH * TT * DD1, tqb1 + l * HH * DD1, h1);
      k_gate<<<bc * HH * (TT / 4), 256, 0, stream>>>(
          h1, xv, tqW2 + (size_t)l * HH * DD1 * DD1, tqb2 + l * HH * DD1,
          tqW3 + (size_t)l * HH * DD1 * 2, tqb3 + l * HH * 2, auv);
      k_merge<<<bc * TT, 64, 0, stream>>>(x, auv, Wlt + (size_t)l * HH * NN * NN,
                                          ln1g + l * NN, ln1b + l * NN, out1);
      k_ffn<<<bc * TT, 64, 0, stream>>>(out1, ws + (size_t)l * 4096, sclb + l,
                                        elW + (size_t)l * NN * NN, elb + l * NN,
                                        ln2g + l * NN, ln2b + l * NN, x);
    }
    k_final<<<bc, 64, 0, stream>>>(x, fW1, fb1, fW2, fb2, out + b0);
  }
}

// Round 2
// 555.422 us; speedup vs baseline: 2.4552x; 2.4552x over previous
//
#include <hip/hip_runtime.h>

typedef __attribute__((ext_vector_type(8))) short short8;
typedef __attribute__((ext_vector_type(4))) float f32x4;

#define BB 8
#define TT 1024
#define NN 64
#define HH 8
#define LL 2
#define KSS 3
#define DD1 64
#define EPSV 1e-6f

#define MFMA16(a, b, c) __builtin_amdgcn_mfma_f32_16x16x32_bf16(a, b, c, 0, 0, 0)

__device__ __forceinline__ ushort f2bf(float x) {
  union { float f; uint u; } v; v.f = x;
  uint r = (v.u + 0x7fffu + ((v.u >> 16) & 1u)) >> 16;
  return (ushort)r;
}
__device__ __forceinline__ float bf2f(ushort b) {
  union { uint u; float f; } v; v.u = ((uint)b) << 16; return v.f;
}

// stage a 64x64 bf16 tile into LDS with 16B-chunk XOR swizzle
__device__ __forceinline__ void stage_tile(ushort* __restrict__ s,
                                           const ushort* __restrict__ g,
                                           int row_stride, int tid) {
#pragma unroll
  for (int i = 0; i < 2; ++i) {
    int idx = tid + i * 256;   // 0..511  (row, 16B-chunk)
    int r = idx >> 3, c = idx & 7;
    uint4 v = *(const uint4*)(g + (size_t)r * row_stride + c * 8);
    *(uint4*)(s + r * 64 + ((c ^ (r & 7)) << 3)) = v;
  }
}

// read 8 contiguous bf16 (one MFMA fragment slice) from swizzled tile
__device__ __forceinline__ short8 frag(const ushort* __restrict__ s, int row, int ch) {
  return *(const short8*)(s + row * 64 + ((ch ^ (row & 7)) << 3));
}

// ---------- small kernels ----------

__global__ void k_addpos(const float* __restrict__ in, const float* __restrict__ pe,
                         float* __restrict__ x, int total) {
  int idx = blockIdx.x * 256 + threadIdx.x;
  if (idx < total) {
    int tn = idx & (TT * NN - 1);
    x[idx] = in[idx] + pe[tn];
  }
}

__global__ void k_k3s(const float* __restrict__ K3, const float* __restrict__ sclwl,
                      float* __restrict__ K3s) {
  int idx = blockIdx.x * 256 + threadIdx.x;  // < 4096
  int n = idx >> 6, m = idx & 63;
  K3s[idx] = K3[n * 192 + m] * sclwl[0] + K3[n * 192 + 64 + m] * sclwl[1] +
             K3[n * 192 + 128 + m] * sclwl[2];
}

// transpose+split: src [mat][1024][64] f32 -> dh/dl [mat][64][1024] bf16 hi/lo
__global__ __launch_bounds__(256) void k_tsplit(const float* __restrict__ src,
                                                ushort* __restrict__ dh,
                                                ushort* __restrict__ dl) {
  __shared__ float st[64][65];
  int blk = blockIdx.x;
  int mat = blk >> 4, rt = blk & 15;
  int tid = threadIdx.x;
  size_t sbase = ((size_t)mat * TT + rt * 64) * 64;
#pragma unroll
  for (int i = 0; i < 4; ++i) {
    int idx = tid + i * 256;
    int r = idx >> 4, c4 = idx & 15;
    float4 v = *(const float4*)(src + sbase + r * 64 + c4 * 4);
    st[r][c4 * 4 + 0] = v.x; st[r][c4 * 4 + 1] = v.y;
    st[r][c4 * 4 + 2] = v.z; st[r][c4 * 4 + 3] = v.w;
  }
  __syncthreads();
  size_t obase = (size_t)mat * (64 * (size_t)TT) + rt * 64;
#pragma unroll
  for (int i = 0; i < 2; ++i) {
    int idx = tid + i * 256;
    int n = idx >> 3, c = idx & 7;
    uint hw[4], lw[4];
#pragma unroll
    for (int j = 0; j < 4; ++j) {
      float v0 = st[c * 8 + 2 * j][n], v1 = st[c * 8 + 2 * j + 1][n];
      ushort h0 = f2bf(v0), h1v = f2bf(v1);
      ushort l0 = f2bf(v0 - bf2f(h0)), l1v = f2bf(v1 - bf2f(h1v));
      hw[j] = (uint)h0 | ((uint)h1v << 16);
      lw[j] = (uint)l0 | ((uint)l1v << 16);
    }
    *(uint4*)(dh + obase + (size_t)n * TT + c * 8) = make_uint4(hw[0], hw[1], hw[2], hw[3]);
    *(uint4*)(dl + obase + (size_t)n * TT + c * 8) = make_uint4(lw[0], lw[1], lw[2], lw[3]);
  }
}

__global__ __launch_bounds__(64) void k_gconv(
    const float* __restrict__ x, const float* __restrict__ K3,
    const float* __restrict__ qwl, const float* __restrict__ qbl,
    const float* __restrict__ kwl, const float* __restrict__ kbl,
    const float* __restrict__ vwl, const float* __restrict__ vbl,
    ushort* __restrict__ xqh, ushort* __restrict__ xql,
    ushort* __restrict__ xkh, ushort* __restrict__ xkl, float* __restrict__ xv) {
  __shared__ float sx[64];
  int lane = threadIdx.x;
  size_t bt = blockIdx.x;
  size_t b = bt >> 10, t = bt & 1023;
  float xm = x[bt * 64 + lane];
  sx[lane] = xm;
  __syncthreads();
  float a0 = 0.f, a1 = 0.f, a2 = 0.f;
#pragma unroll 4
  for (int n = 0; n < 64; ++n) {
    float xn = sx[n];
    a0 = fmaf(xn, K3[n * 192 + lane], a0);
    a1 = fmaf(xn, K3[n * 192 + 64 + lane], a1);
    a2 = fmaf(xn, K3[n * 192 + 128 + lane], a2);
  }
#pragma unroll
  for (int hh = 0; hh < HH; ++hh) {
    size_t off = (((size_t)b * HH + hh) * TT + t) * 64 + lane;
    float q = fmaf(qwl[hh * 3 + 0], a0,
              fmaf(qwl[hh * 3 + 1], a1, fmaf(qwl[hh * 3 + 2], a2, qbl[hh] + xm)));
    q = fmaxf(q, 0.f) * 0.015625f;   // fold 1/N score scale into Q
    ushort qh = f2bf(q);
    xqh[off] = qh; xql[off] = f2bf(q - bf2f(qh));
    float k = fmaf(kwl[hh * 3 + 0], a0,
              fmaf(kwl[hh * 3 + 1], a1, fmaf(kwl[hh * 3 + 2], a2, kbl[hh] + xm)));
    k = fmaxf(k, 0.f);
    ushort kh = f2bf(k);
    xkh[off] = kh; xkl[off] = f2bf(k - bf2f(kh));
    float v = fmaf(vwl[hh * 3 + 0], a0,
              fmaf(vwl[hh * 3 + 1], a1, fmaf(vwl[hh * 3 + 2], a2, vbl[hh] + xm)));
    xv[off] = fmaxf(v, 0.f);
  }
}

// ---------- pass A: flash attention via bf16-split MFMA ----------
// block: one (bh, 64-row t-tile); scores computed transposed: C[u][t]
__global__ __launch_bounds__(256, 3) void k_attn(
    const ushort* __restrict__ xkh, const ushort* __restrict__ xkl,
    const ushort* __restrict__ xqh, const ushort* __restrict__ xql,
    const ushort* __restrict__ xvTh, const ushort* __restrict__ xvTl,
    float* __restrict__ auv, float* __restrict__ lse) {
  __shared__ ushort sKh[4096], sKl[4096], sQh[4096], sQl[4096], sVh[4096], sVl[4096];
  int tid = threadIdx.x;
  int lane = tid & 63, w = tid >> 6;
  int l15 = lane & 15, g = lane >> 4;
  int blk = blockIdx.x;
  int bh = blk >> 4, t0 = (blk & 15) << 6;
  size_t tileK = ((size_t)bh * TT + t0) * NN;
  stage_tile(sKh, xkh + tileK, 64, tid);
  stage_tile(sKl, xkl + tileK, 64, tid);
  __syncthreads();
  short8 fKh[2], fKl[2];  // B-frag: cols t = t0+16w+l15, persistent
#pragma unroll
  for (int ks = 0; ks < 2; ++ks) {
    fKh[ks] = frag(sKh, 16 * w + l15, g + 4 * ks);
    fKl[ks] = frag(sKl, 16 * w + l15, g + 4 * ks);
  }
  float m = -3.0e38f, lsum = 0.f;
  f32x4 O[4];
#pragma unroll
  for (int ct = 0; ct < 4; ++ct)
#pragma unroll
    for (int r = 0; r < 4; ++r) O[ct][r] = 0.f;

  for (int ut = 0; ut < 16; ++ut) {
    __syncthreads();
    size_t tq = ((size_t)bh * TT + ut * 64) * NN;
    size_t tv = (size_t)bh * (NN * (size_t)TT) + ut * 64;
    stage_tile(sQh, xqh + tq, 64, tid);
    stage_tile(sQl, xql + tq, 64, tid);
    stage_tile(sVh, xvTh + tv, 1024, tid);
    stage_tile(sVl, xvTl + tv, 1024, tid);
    __syncthreads();
    // scores S[u][t]: A = Q rows u, B = K cols t; 3-term split
    f32x4 S[4];
#pragma unroll
    for (int rt = 0; rt < 4; ++rt) {
      f32x4 acc = {0.f, 0.f, 0.f, 0.f};
#pragma unroll
      for (int ks = 0; ks < 2; ++ks) {
        short8 aQh = frag(sQh, 16 * rt + l15, g + 4 * ks);
        short8 aQl = frag(sQl, 16 * rt + l15, g + 4 * ks);
        acc = MFMA16(aQh, fKh[ks], acc);
        acc = MFMA16(aQh, fKl[ks], acc);
        acc = MFMA16(aQl, fKh[ks], acc);
      }
      S[rt] = acc;
    }
    // per-lane online softmax over u (lane owns t = t0+16w+l15)
    float tmax = -3.0e38f;
#pragma unroll
    for (int rt = 0; rt < 4; ++rt)
#pragma unroll
      for (int r = 0; r < 4; ++r) tmax = fmaxf(tmax, S[rt][r]);
    tmax = fmaxf(tmax, __shfl_xor(tmax, 16, 64));
    tmax = fmaxf(tmax, __shfl_xor(tmax, 32, 64));
    float mnew = fmaxf(m, tmax);
    float psum = 0.f;
    uint2 ph[4], pl[4];
#pragma unroll
    for (int rt = 0; rt < 4; ++rt) {
      ushort hh[4], ll[4];
#pragma unroll
      for (int r = 0; r < 4; ++r) {
        float p = __expf(S[rt][r] - mnew);
        psum += p;
        ushort hb = f2bf(p);
        hh[r] = hb;
        ll[r] = f2bf(p - bf2f(hb));
      }
      ph[rt] = make_uint2((uint)hh[0] | ((uint)hh[1] << 16), (uint)hh[2] | ((uint)hh[3] << 16));
      pl[rt] = make_uint2((uint)ll[0] | ((uint)ll[1] << 16), (uint)ll[2] | ((uint)ll[3] << 16));
    }
    psum += __shfl_xor(psum, 16, 64);
    psum += __shfl_xor(psum, 32, 64);
    float f = __expf(m - mnew);
    lsum = lsum * f + psum;
    m = mnew;
    // rescale O (rows t = 16w+4g+r) with f broadcast from lane holding that t
    float fr[4];
#pragma unroll
    for (int r = 0; r < 4; ++r) fr[r] = __shfl(f, (lane & 48) | (4 * g + r), 64);
#pragma unroll
    for (int ct = 0; ct < 4; ++ct)
#pragma unroll
      for (int r = 0; r < 4; ++r) O[ct][r] *= fr[r];
    __syncthreads();
    // write P' = P[t][u] (row-major, swizzled) into Q buffers
    {
      int trow = 16 * w + l15;
      int sw = trow & 7;
#pragma unroll
      for (int rt = 0; rt < 4; ++rt) {
        int ch = 2 * rt + (g >> 1);
        int off = trow * 64 + ((ch ^ sw) << 3) + ((g & 1) << 2);
        *(uint2*)(sQh + off) = ph[rt];
        *(uint2*)(sQl + off) = pl[rt];
      }
    }
    __syncthreads();
    // O[t][n] += P'[t][u] * V[u][n]   (B from V^T tile)
#pragma unroll
    for (int ks = 0; ks < 2; ++ks) {
      short8 aPh = frag(sQh, 16 * w + l15, g + 4 * ks);
      short8 aPl = frag(sQl, 16 * w + l15, g + 4 * ks);
#pragma unroll
      for (int ct = 0; ct < 4; ++ct) {
        short8 bVh = frag(sVh, 16 * ct + l15, g + 4 * ks);
        short8 bVl = frag(sVl, 16 * ct + l15, g + 4 * ks);
        O[ct] = MFMA16(aPh, bVh, O[ct]);
        O[ct] = MFMA16(aPh, bVl, O[ct]);
        O[ct] = MFMA16(aPl, bVh, O[ct]);
      }
    }
  }
  float il = 1.0f / lsum;
  float ilr[4];
#pragma unroll
  for (int r = 0; r < 4; ++r) ilr[r] = __shfl(il, (lane & 48) | (4 * g + r), 64);
#pragma unroll
  for (int r = 0; r < 4; ++r) {
    size_t row = ((size_t)bh * TT + t0 + 16 * w + 4 * g + r) * NN;
#pragma unroll
    for (int ct = 0; ct < 4; ++ct) auv[row + 16 * ct + l15] = O[ct][r] * ilr[r];
  }
  if (g == 0) lse[(size_t)bh * TT + t0 + 16 * w + l15] = m + __logf(lsum);
}

// ---------- pass B: h1[a][d] = relu(sum_t P[t][a] * W1[t][d] + b1[d]) ----------
__global__ __launch_bounds__(256, 3) void k_h1(
    const ushort* __restrict__ xkh, const ushort* __restrict__ xkl,
    const ushort* __restrict__ xqh, const ushort* __restrict__ xql,
    const ushort* __restrict__ w1Th, const ushort* __restrict__ w1Tl,
    const float* __restrict__ lse, const float* __restrict__ b1,
    float* __restrict__ h1) {
  __shared__ ushort sQh[4096], sQl[4096], sKh[4096], sKl[4096], sWh[4096], sWl[4096];
  __shared__ float sL[64];
  int tid = threadIdx.x;
  int lane = tid & 63, w = tid >> 6;
  int l15 = lane & 15, g = lane >> 4;
  int blk = blockIdx.x;
  int bh = blk >> 4, h = bh & (HH - 1), a0 = (blk & 15) << 6;
  size_t tq = ((size_t)bh * TT + a0) * NN;
  stage_tile(sQh, xqh + tq, 64, tid);
  stage_tile(sQl, xql + tq, 64, tid);
  __syncthreads();
  short8 fQh[2], fQl[2];  // B-frag: cols a = a0+16w+l15, persistent
#pragma unroll
  for (int ks = 0; ks < 2; ++ks) {
    fQh[ks] = frag(sQh, 16 * w + l15, g + 4 * ks);
    fQl[ks] = frag(sQl, 16 * w + l15, g + 4 * ks);
  }
  f32x4 acc[4];
#pragma unroll
  for (int ct = 0; ct < 4; ++ct)
#pragma unroll
    for (int r = 0; r < 4; ++r) acc[ct][r] = 0.f;

  for (int tt = 0; tt < 16; ++tt) {
    __syncthreads();
    size_t tk = ((size_t)bh * TT + tt * 64) * NN;
    size_t twt = (size_t)h * (NN * (size_t)TT) + tt * 64;
    stage_tile(sKh, xkh + tk, 64, tid);
    stage_tile(sKl, xkl + tk, 64, tid);
    stage_tile(sWh, w1Th + twt, 1024, tid);
    stage_tile(sWl, w1Tl + twt, 1024, tid);
    if (tid < 64) sL[tid] = lse[(size_t)bh * TT + tt * 64 + tid];
    __syncthreads();
    // scores S[t][a]: A = K rows t, B = Q cols a
    f32x4 S[4];
#pragma unroll
    for (int rt = 0; rt < 4; ++rt) {
      f32x4 a2 = {0.f, 0.f, 0.f, 0.f};
#pragma unroll
      for (int ks = 0; ks < 2; ++ks) {
        short8 aKh = frag(sKh, 16 * rt + l15, g + 4 * ks);
        short8 aKl = frag(sKl, 16 * rt + l15, g + 4 * ks);
        a2 = MFMA16(aKh, fQh[ks], a2);
        a2 = MFMA16(aKh, fQl[ks], a2);
        a2 = MFMA16(aKl, fQh[ks], a2);
      }
      S[rt] = a2;
    }
    // P = exp(S - lse_t), lane owns a = a0+16w+l15, t = 16rt+4g+r
    uint2 ph[4], pl[4];
#pragma unroll
    for (int rt = 0; rt < 4; ++rt) {
      ushort hh[4], ll[4];
#pragma unroll
      for (int r = 0; r < 4; ++r) {
        float p = __expf(S[rt][r] - sL[16 * rt + 4 * g + r]);
        ushort hb = f2bf(p);
        hh[r] = hb;
        ll[r] = f2bf(p - bf2f(hb));
      }
      ph[rt] = make_uint2((uint)hh[0] | ((uint)hh[1] << 16), (uint)hh[2] | ((uint)hh[3] << 16));
      pl[rt] = make_uint2((uint)ll[0] | ((uint)ll[1] << 16), (uint)ll[2] | ((uint)ll[3] << 16));
    }
    __syncthreads();
    // write P'[a][t] over K buffers
    {
      int arow = 16 * w + l15;
      int sw = arow & 7;
#pragma unroll
      for (int rt = 0; rt < 4; ++rt) {
        int ch = 2 * rt + (g >> 1);
        int off = arow * 64 + ((ch ^ sw) << 3) + ((g & 1) << 2);
        *(uint2*)(sKh + off) = ph[rt];
        *(uint2*)(sKl + off) = pl[rt];
      }
    }
    __syncthreads();
    // acc[a][d] += P'[a][t] * W1[t][d]  (B from W1^T tile)
#pragma unroll
    for (int ks = 0; ks < 2; ++ks) {
      short8 aPh = frag(sKh, 16 * w + l15, g + 4 * ks);
      short8 aPl = frag(sKl, 16 * w + l15, g + 4 * ks);
#pragma unroll
      for (int ct = 0; ct < 4; ++ct) {
        short8 bWh = frag(sWh, 16 * ct + l15, g + 4 * ks);
        short8 bWl = frag(sWl, 16 * ct + l15, g + 4 * ks);
        acc[ct] = MFMA16(aPh, bWh, acc[ct]);
        acc[ct] = MFMA16(aPh, bWl, acc[ct]);
        acc[ct] = MFMA16(aPl, bWh, acc[ct]);
      }
    }
  }
#pragma unroll
  for (int ct = 0; ct < 4; ++ct) {
    float bb = b1[h * 64 + 16 * ct + l15];
#pragma unroll
    for (int r = 0; r < 4; ++r)
      h1[((size_t)bh * TT + a0 + 16 * w + 4 * g + r) * NN + 16 * ct + l15] =
          fmaxf(acc[ct][r] + bb, 0.f);
  }
}

// ---------- unchanged tail kernels ----------

__global__ __launch_bounds__(256) void k_gate(
    const float* __restrict__ h1, const float* __restrict__ xv,
    const float* __restrict__ W2l, const float* __restrict__ b2l,
    const float* __restrict__ W3l, const float* __restrict__ b3l,
    float* __restrict__ auv) {
  __shared__ float sh1[4][64];
  int tid = threadIdx.x;
  int w = tid >> 6;
  int d = tid & 63;
  size_t blk = blockIdx.x;
  size_t bh = blk >> 8;
  int t = (int)((blk & 255) << 2) + w;
  int h = (int)(bh & (HH - 1));
  size_t rowoff = (bh * TT + (size_t)t) * 64;
  sh1[w][d] = h1[rowoff + d];
  __syncthreads();
  float acc = b2l[h * 64 + d];
  const float* W2 = W2l + (size_t)h * 64 * 64;
#pragma unroll 8
  for (int e = 0; e < 64; ++e) acc = fmaf(sh1[w][e], W2[e * 64 + d], acc);
  acc = fmaxf(acc, 0.f);
  float z0 = acc * W3l[((size_t)h * 64 + d) * 2 + 0];
  float z1 = acc * W3l[((size_t)h * 64 + d) * 2 + 1];
#pragma unroll
  for (int m = 1; m < 64; m <<= 1) {
    z0 += __shfl_xor(z0, m, 64);
    z1 += __shfl_xor(z1, m, 64);
  }
  z0 += b3l[h * 2 + 0];
  z1 += b3l[h * 2 + 1];
  float g0 = 1.0f / (1.0f + __expf(z1 - z0));
  float g1 = 1.0f - g0;
  auv[rowoff + d] = g0 * auv[rowoff + d] + g1 * xv[rowoff + d];
}

__global__ __launch_bounds__(64) void k_merge(
    const float* __restrict__ x, const float* __restrict__ ho,
    const float* __restrict__ Wltl, const float* __restrict__ g1l,
    const float* __restrict__ b1l, float* __restrict__ out1) {
  __shared__ float sho[512];
  int lane = threadIdx.x;
  size_t bt = blockIdx.x;
  size_t b = bt >> 10, t = bt & 1023;
#pragma unroll
  for (int i = 0; i < 8; ++i) {
    int idx = lane + i * 64;
    int hh = idx >> 6, n = idx & 63;
    sho[idx] = ho[(((size_t)b * HH + hh) * TT + t) * 64 + n];
  }
  __syncthreads();
  float acc = x[bt * 64 + lane];
#pragma unroll 8
  for (int hn = 0; hn < 512; ++hn) acc = fmaf(sho[hn], Wltl[hn * 64 + lane], acc);
  float mu = acc;
#pragma unroll
  for (int m = 1; m < 64; m <<= 1) mu += __shfl_xor(mu, m, 64);
  mu *= (1.0f / 64.0f);
  float dd = acc - mu;
  float var = dd * dd;
#pragma unroll
  for (int m = 1; m < 64; m <<= 1) var += __shfl_xor(var, m, 64);
  var *= (1.0f / 64.0f);
  out1[bt * 64 + lane] = dd * rsqrtf(var + EPSV) * g1l[lane] + b1l[lane];
}

__global__ __launch_bounds__(64) void k_ffn(
    const float* __restrict__ out1, const float* __restrict__ K3sl,
    const float* __restrict__ sclb_l, const float* __restrict__ elWl,
    const float* __restrict__ elbl, const float* __restrict__ g2l,
    const float* __restrict__ b2l, float* __restrict__ xout) {
  __shared__ float so[64], sf[64];
  int lane = threadIdx.x;
  size_t bt = blockIdx.x;
  float o1 = out1[bt * 64 + lane];
  so[lane] = o1;
  __syncthreads();
  float gc = 0.f;
#pragma unroll 8
  for (int n = 0; n < 64; ++n) gc = fmaf(so[n], K3sl[n * 64 + lane], gc);
  float f1 = fmaxf(gc + sclb_l[0] + o1, 0.f);
  sf[lane] = f1;
  __syncthreads();
  float f2 = elbl[lane];
#pragma unroll 8
  for (int e = 0; e < 64; ++e) f2 = fmaf(sf[e], elWl[e * 64 + lane], f2);
  float v = o1 + f2;
  float mu = v;
#pragma unroll
  for (int m = 1; m < 64; m <<= 1) mu += __shfl_xor(mu, m, 64);
  mu *= (1.0f / 64.0f);
  float dd = v - mu;
  float var = dd * dd;
#pragma unroll
  for (int m = 1; m < 64; m <<= 1) var += __shfl_xor(var, m, 64);
  var *= (1.0f / 64.0f);
  xout[bt * 64 + lane] = dd * rsqrtf(var + EPSV) * g2l[lane] + b2l[lane];
}

__global__ __launch_bounds__(64) void k_final(
    const float* __restrict__ x, const float* __restrict__ fW1,
    const float* __restrict__ fb1, const float* __restrict__ fW2,
    const float* __restrict__ fb2, float* __restrict__ out) {
  __shared__ float pl[64];
  int lane = threadIdx.x;
  size_t b = blockIdx.x;
  float s = 0.f;
  for (int t = 0; t < TT; ++t) s += x[((size_t)b * TT + t) * 64 + lane];
  pl[lane] = s * (1.0f / TT);
  __syncthreads();
  float hv = 0.f;
  if (lane < 32) {
    hv = fb1[lane];
#pragma unroll 8
    for (int n = 0; n < 64; ++n) hv = fmaf(pl[n], fW1[n * 32 + lane], hv);
    hv = fmaxf(hv, 0.f) * fW2[lane];
  }
#pragma unroll
  for (int m = 1; m < 64; m <<= 1) hv += __shfl_xor(hv, m, 64);
  if (lane == 0) out[b] = hv + fb2[0];
}

extern "C" void kernel_launch(void* const* d_in, const int* in_sizes, int n_in,
                              void* d_out, int out_size, void* d_ws, size_t ws_size,
                              hipStream_t stream) {
  const float* inputs = (const float*)d_in[0];
  const float* pos_emb = (const float*)d_in[1];
  const float* K3 = (const float*)d_in[2];
  const float* qw = (const float*)d_in[3];
  const float* qb = (const float*)d_in[4];
  const float* kw = (const float*)d_in[5];
  const float* kb = (const float*)d_in[6];
  const float* vw = (const float*)d_in[7];
  const float* vb = (const float*)d_in[8];
  const float* tqW1 = (const float*)d_in[9];
  const float* tqb1 = (const float*)d_in[10];
  const float* tqW2 = (const float*)d_in[11];
  const float* tqb2 = (const float*)d_in[12];
  const float* tqW3 = (const float*)d_in[13];
  const float* tqb3 = (const float*)d_in[14];
  const float* Wlt = (const float*)d_in[15];
  const float* ln1g = (const float*)d_in[16];
  const float* ln1b = (const float*)d_in[17];
  const float* ln2g = (const float*)d_in[18];
  const float* ln2b = (const float*)d_in[19];
  const float* sclw = (const float*)d_in[20];
  const float* sclb = (const float*)d_in[21];
  const float* elW = (const float*)d_in[22];
  const float* elb = (const float*)d_in[23];
  const float* fW1 = (const float*)d_in[24];
  const float* fb1 = (const float*)d_in[25];
  const float* fW2 = (const float*)d_in[26];
  const float* fb2 = (const float*)d_in[27];
  float* out = (float*)d_out;
  float* ws_f = (float*)d_ws;

  const size_t TN = (size_t)TT * NN;          // 65536
  const size_t HTN = (size_t)HH * TT * NN;    // 524288
  const size_t W1T_ELEMS = (size_t)LL * HH * NN * TT;  // ushorts per array

  float* K3s = ws_f;                                 // 2*4096 words
  ushort* w1Th = (ushort*)(ws_f + 2 * 4096);         // W1T_ELEMS ushorts
  ushort* w1Tl = w1Th + W1T_ELEMS;
  const size_t base = 2 * 4096 + W1T_ELEMS;          // words (W1T_ELEMS/2 *2 arrays)

  for (int l = 0; l < LL; ++l)
    k_k3s<<<16, 256, 0, stream>>>(K3, sclw + l * KSS, K3s + (size_t)l * 4096);
  k_tsplit<<<LL * HH * 16, 256, 0, stream>>>(tqW1, w1Th, w1Tl);  // 16 mats

  const size_t per_b = 2 * TN + 3 * HTN + (size_t)HH * TT + 3 * HTN;  // words
  size_t avail = ws_size / sizeof(float);
  avail = (avail > base) ? avail - base : 0;
  int Bc = (int)(avail / per_b);
  if (Bc > BB) Bc = BB;
  if (Bc < 1) Bc = 1;

  for (int b0 = 0; b0 < BB; b0 += Bc) {
    int bc = (BB - b0 < Bc) ? (BB - b0) : Bc;
    float* x = ws_f + base;
    float* out1 = x + (size_t)bc * TN;
    float* xv = out1 + (size_t)bc * TN;
    float* auv = xv + (size_t)bc * HTN;
    float* h1 = auv + (size_t)bc * HTN;
    float* lseb = h1 + (size_t)bc * HTN;
    ushort* xqh = (ushort*)(lseb + (size_t)bc * HH * TT);
    ushort* xql = xqh + (size_t)bc * HTN;
    ushort* xkh = xql + (size_t)bc * HTN;
    ushort* xkl = xkh + (size_t)bc * HTN;
    ushort* xvTh = xkl + (size_t)bc * HTN;
    ushort* xvTl = xvTh + (size_t)bc * HTN;

    int total = bc * (int)TN;
    k_addpos<<<(total + 255) / 256, 256, 0, stream>>>(inputs + (size_t)b0 * TN, pos_emb, x,
                                                      total);
    for (int l = 0; l < LL; ++l) {
      k_gconv<<<bc * TT, 64, 0, stream>>>(x, K3, qw + l * HH * KSS, qb + l * HH,
                                          kw + l * HH * KSS, kb + l * HH,
                                          vw + l * HH * KSS, vb + l * HH,
                                          xqh, xql, xkh, xkl, xv);
      k_tsplit<<<bc * HH * 16, 256, 0, stream>>>(xv, xvTh, xvTl);
      k_attn<<<bc * HH * 16, 256, 0, stream>>>(xkh, xkl, xqh, xql, xvTh, xvTl, auv, lseb);
      k_h1<<<bc * HH * 16, 256, 0, stream>>>(
          xkh, xkl, xqh, xql, w1Th + (size_t)l * HH * NN * TT,
          w1Tl + (size_t)l * HH * NN * TT, lseb, tqb1 + l * HH * DD1, h1);
      k_gate<<<bc * HH * (TT / 4), 256, 0, stream>>>(
          h1, xv, tqW2 + (size_t)l * HH * DD1 * DD1, tqb2 + l * HH * DD1,
          tqW3 + (size_t)l * HH * DD1 * 2, tqb3 + l * HH * 2, auv);
      k_merge<<<bc * TT, 64, 0, stream>>>(x, auv, Wlt + (size_t)l * HH * NN * NN,
                                          ln1g + l * NN, ln1b + l * NN, out1);
      k_ffn<<<bc * TT, 64, 0, stream>>>(out1, K3s + (size_t)l * 4096, sclb + l,
                                        elW + (size_t)l * NN * NN, elb + l * NN,
                                        ln2g + l * NN, ln2b + l * NN, x);
    }
    k_final<<<bc, 64, 0, stream>>>(x, fW1, fb1, fW2, fb2, out + b0);
  }
}